// Round 21
// baseline (133.230 us; speedup 1.0000x reference)
//
#include <hip/hip_runtime.h>
#include <math.h>

// Problem constants (reference: B=2, S=2048, D=1024, H=16, HD=64)
#define B_ 2
#define S_ 2048
#define D_ 1024
#define H_ 16
#define HD_ 64

typedef unsigned short ushort8 __attribute__((ext_vector_type(8)));
typedef unsigned int u32x4 __attribute__((ext_vector_type(4)));
typedef _Float16 f16x8 __attribute__((ext_vector_type(8)));
typedef _Float16 f16x2 __attribute__((ext_vector_type(2)));
typedef float f32x4 __attribute__((ext_vector_type(4)));

__device__ __forceinline__ unsigned short f2h(float f) {
    union { _Float16 h; unsigned short u; } v;
    v.h = (_Float16)f;                     // native v_cvt_f16_f32, RNE
    return v.u;
}
__device__ __forceinline__ float h2f(unsigned short u) {
    union { unsigned short u; _Float16 h; } v; v.u = u;
    return (float)v.h;
}
__device__ __forceinline__ ushort8 pack2x4h(f32x4 a, f32x4 b) {
    ushort8 hi;
    #pragma unroll
    for (int i = 0; i < 4; ++i) { hi[i] = f2h(a[i]); hi[4 + i] = f2h(b[i]); }
    return hi;
}

// XOR swizzle for [R][64] f16 tiles (128B rows): in-row 16B-chunk permute by row&7.
#define SWZ(row, col) ((((row)) << 6) + (((col)) ^ ((((row)) & 7) << 3)))

__device__ __forceinline__ f32x4 mfma16(f16x8 a, f16x8 b, f32x4 c) {
    return __builtin_amdgcn_mfma_f32_16x16x32_f16(a, b, c, 0, 0, 0);
}

typedef __attribute__((address_space(1))) const void gvoid_t;
typedef __attribute__((address_space(3))) void lvoid_t;
typedef __attribute__((address_space(3))) unsigned short lds_us_t;
__device__ __forceinline__ void gload_lds16(const void* g, void* l) {
    __builtin_amdgcn_global_load_lds((gvoid_t*)g, (lvoid_t*)l, 16, 0, 0);
}
// inline-asm LDS read: opaque to the compiler's waitcnt pass (counted vmcnt survives)
__device__ __forceinline__ f16x8 dsr128(unsigned addr) {
    u32x4 r;
    asm volatile("ds_read_b128 %0, %1" : "=v"(r) : "v"(addr));
    union { u32x4 u; f16x8 h; } cv; cv.u = r; return cv.h;
}

// exp(s*0.125) == 2^(s * 0.125*log2e); raw v_exp_f32 (natively 2^x, no libm tail).
#define EXPSC 0.18033688011f
#define EXP2R(x) __builtin_amdgcn_exp2f(x)

// ---------------------------------------------------------------------------
// conv_rows: fp32 [4096][1024] -> fp16 hi, pre-swizzled (key = row&7)
// ---------------------------------------------------------------------------
__global__ __launch_bounds__(256) void conv_rows_kernel(
    const float* __restrict__ in, unsigned short* __restrict__ ohi)
{
    const int id = blockIdx.x * 256 + threadIdx.x;   // [0, 4096*128)
    const int r = id >> 7, c = id & 127;
    const float* s = in + (size_t)r * 1024 + c * 8;
    f32x4 v0 = *(const f32x4*)s, v1 = *(const f32x4*)(s + 4);
    ushort8 hi = pack2x4h(v0, v1);
    const int oc = (c & ~7) | ((c ^ r) & 7);
    *(ushort8*)&ohi[(size_t)r * 1024 + oc * 8] = hi;
}

// ---------------------------------------------------------------------------
// conv_wt (merged, hi-only): grid (16, 64): y<48 -> W_qkv (ldw 3072), else
// W_out (ldw 1024). fp32 -> Wt fp16 hi [N][1024], transposed + pre-swizzled.
// ---------------------------------------------------------------------------
__global__ __launch_bounds__(256) void conv_wt_kernel(
    const float* __restrict__ Wq, const float* __restrict__ Wo,
    unsigned short* __restrict__ Wqh, unsigned short* __restrict__ Woh)
{
    __shared__ float T[64][65];
    const float* W; int ldw, ny;
    unsigned short *oh;
    if (blockIdx.y < 48) { W = Wq; ldw = 3072; ny = blockIdx.y * 64; oh = Wqh; }
    else                 { W = Wo; ldw = 1024; ny = (blockIdx.y - 48) * 64; oh = Woh; }
    const int tid = threadIdx.x;
    const int kx = blockIdx.x * 64;
    const int kl = tid >> 2, c0 = (tid & 3) * 16;
    const float* s = W + (size_t)(kx + kl) * ldw + ny + c0;
    #pragma unroll
    for (int i = 0; i < 4; ++i) *(f32x4*)&T[kl][c0 + 4 * i] = *(const f32x4*)(s + 4 * i);
    __syncthreads();
    const int nl = tid >> 2, jj = (tid & 3) * 2;
    #pragma unroll
    for (int p = 0; p < 2; ++p) {
        const int j = jj + p;
        f32x4 a, b;
        #pragma unroll
        for (int i = 0; i < 4; ++i) a[i] = T[j * 8 + i][nl];
        #pragma unroll
        for (int i = 0; i < 4; ++i) b[i] = T[j * 8 + 4 + i][nl];
        ushort8 hi = pack2x4h(a, b);
        const int row = ny + nl;
        const int chunk = blockIdx.x * 8 + (j ^ (nl & 7));
        *(ushort8*)&oh[(size_t)row * 1024 + chunk * 8] = hi;
    }
}

// ---------------------------------------------------------------------------
// Pure fp16 MFMA GEMM (1-term, r16-r20 proven): C = Ah @ Bth^T (+ bias).
// 128x128 tile, BK=32, 2 x 16KB LDS dbuf, 4 blocks/CU, counted vmcnt(4).
// OUTMODE 1: fp16 hi out (+bias). OUTMODE 2: split-K fp32.
// ---------------------------------------------------------------------------
template<int OUTMODE>
__global__ __launch_bounds__(256, 4) void gemm16_kernel(
    const unsigned short* __restrict__ Ah, const unsigned short* __restrict__ Bth,
    const float* __restrict__ bias, float* __restrict__ Cf, float* __restrict__ Cf1,
    unsigned short* __restrict__ Ohi,
    int M, int N, int K)
{
    __shared__ __align__(16) unsigned short lds[16384];   // 32KB: 2 x 16KB buffers

    const int tid = threadIdx.x, lane = tid & 63, w = tid >> 6;
    const int wm = w >> 1, wn = w & 1;
    const int gx = gridDim.x, nwg = gx * gridDim.y;
    const int lin = blockIdx.y * gx + blockIdx.x;
    const int nl = (lin & 7) * (nwg >> 3) + (lin >> 3);
    int mblk = nl / gx;
    int koff = 0;
    float* Cfw = Cf;
    bool dobias = (OUTMODE != 2);
    if (OUTMODE == 2) {
        const int halfrows = (int)(gridDim.y >> 1);
        if (mblk >= halfrows) { mblk -= halfrows; koff = 512; Cfw = Cf1; dobias = false; }
        else dobias = true;
    }
    const int m0 = mblk * 128, n0 = (nl % gx) * 128;
    const int col = lane & 15, g = lane >> 4;
    const int NT = K >> 5;

    const int sr0 = (w * 2 + 0) * 16 + (lane >> 2);
    const int sr1 = (w * 2 + 1) * 16 + (lane >> 2);
    const int scp = lane & 3;

    auto stage = [&](int tt) {
        unsigned short* dst = &lds[(tt & 1) * 8192];
        const int hi8 = (tt >> 1) * 8;
        const int tb4 = (tt & 1) << 2;
        #pragma unroll
        for (int q = 0; q < 2; ++q) {
            const int r = q ? sr1 : sr0;
            const int p = hi8 + ((tb4 ^ (r & 4)) | (scp ^ ((r >> 2) & 3)));
            const size_t go = (size_t)p * 8 + koff;
            const int slotb = (w * 2 + q) * 512;
            gload_lds16(Ah  + (size_t)(m0 + r) * 1024 + go, dst + 0    + slotb);
            gload_lds16(Bth + (size_t)(n0 + r) * 1024 + go, dst + 4096 + slotb);
        }
    };

    const unsigned ldsb = (unsigned)(size_t)(lds_us_t*)lds;
    const unsigned sk = (unsigned)(((g ^ (col & 3) ^ ((col >> 2) & 3)) & 3) << 4);
    const unsigned aB = ldsb + (unsigned)((wm * 64 + col) * 64) + sk;
    const unsigned bB = ldsb + 8192u + (unsigned)((wn * 64 + col) * 64) + sk;

    f32x4 acc[4][4] = {};

    stage(0);
    stage(1);

    for (int tt = 0; tt < NT; ++tt) {
        if (tt + 1 < NT) asm volatile("s_waitcnt vmcnt(4)" ::: "memory");
        else             asm volatile("s_waitcnt vmcnt(0)" ::: "memory");
        __builtin_amdgcn_s_barrier();
        __builtin_amdgcn_sched_barrier(0);
        const unsigned bo = (unsigned)((tt & 1) * 16384);

        f16x8 a[4], b[4];
        #pragma unroll
        for (int i = 0; i < 4; ++i) a[i] = dsr128(aB + bo + i * 1024u);
        #pragma unroll
        for (int i = 0; i < 4; ++i) b[i] = dsr128(bB + bo + i * 1024u);

        asm volatile("s_waitcnt lgkmcnt(0)" ::: "memory");
        __builtin_amdgcn_sched_barrier(0);
        __builtin_amdgcn_s_setprio(1);
        #pragma unroll
        for (int mi = 0; mi < 4; ++mi)
            #pragma unroll
            for (int nj = 0; nj < 4; ++nj)
                acc[mi][nj] = mfma16(a[mi], b[nj], acc[mi][nj]);
        __builtin_amdgcn_s_setprio(0);
        __builtin_amdgcn_s_barrier();
        __builtin_amdgcn_sched_barrier(0);
        if (tt + 2 < NT) stage(tt + 2);
    }

    // ---- epilogue: per-wave LDS transpose in two 32-row halves ----
    __syncthreads();
    float* ow = (float*)((char*)lds + w * 8192);   // [32][64] fp32 per wave
    const int nc = (lane & 7) * 8;
    const int nabs = n0 + wn * 64 + nc;
    f32x4 bi0 = {}, bi1 = {};
    if (dobias) { bi0 = *(const f32x4*)&bias[nabs]; bi1 = *(const f32x4*)&bias[nabs + 4]; }
    #pragma unroll
    for (int half = 0; half < 2; ++half) {
        __builtin_amdgcn_wave_barrier();
        #pragma unroll
        for (int ml = 0; ml < 2; ++ml)
            #pragma unroll
            for (int nj = 0; nj < 4; ++nj)
                #pragma unroll
                for (int r = 0; r < 4; ++r)
                    ow[(ml * 16 + g * 4 + r) * 64 + nj * 16 + col] = acc[half * 2 + ml][nj][r];
        __builtin_amdgcn_wave_barrier();
        #pragma unroll
        for (int it = 0; it < 4; ++it) {
            const int rl = it * 8 + (lane >> 3);
            f32x4 v0 = *(const f32x4*)&ow[rl * 64 + nc];
            f32x4 v1 = *(const f32x4*)&ow[rl * 64 + nc + 4];
            if (dobias) { v0 += bi0; v1 += bi1; }
            const int m = m0 + wm * 64 + half * 32 + rl;
            if (OUTMODE == 1) {
                ushort8 hi = pack2x4h(v0, v1);
                const int chunk = (lane & 7) ^ (m & 7);
                *(ushort8*)&Ohi[(size_t)m * N + n0 + wn * 64 + chunk * 8] = hi;
            } else {
                *(f32x4*)&Cfw[(size_t)m * N + nabs] = v0;
                *(f32x4*)&Cfw[(size_t)m * N + nabs + 4] = v1;
            }
        }
        __builtin_amdgcn_wave_barrier();
    }
}

// ---------------------------------------------------------------------------
// out += p1   (split-K combine)
// ---------------------------------------------------------------------------
__global__ __launch_bounds__(256) void addp_kernel(
    float* __restrict__ out, const float* __restrict__ p1)
{
    const size_t idx = ((size_t)blockIdx.x * 256 + threadIdx.x) * 4;
    f32x4 v = *(const f32x4*)&out[idx];
    f32x4 u = *(const f32x4*)&p1[idx];
    v += u;
    *(f32x4*)&out[idx] = v;
}

// ---------------------------------------------------------------------------
// V suffix tile sums (hi-only), batched: grid (32, 8); blockIdx.x = b*16+h
// ---------------------------------------------------------------------------
__global__ __launch_bounds__(256) void vsuf_part_kernel(
    const unsigned short* __restrict__ qh, float* __restrict__ tsum)
{
    const int bh = blockIdx.x, tg = blockIdx.y;
    const int b = bh >> 4, h = bh & 15;
    const unsigned short* qhB = qh + (size_t)b * 2048 * 3072;
    const int tl = threadIdx.x >> 6, lane = threadIdx.x & 63;
    const int t = tg * 4 + tl;
    const int dgrp = lane & 7, rr = lane >> 3;
    const int colbase = h * 192 + 128;
    float sacc[8] = {};
    for (int kk = 0; kk < 8; ++kk) {
        const int row = t * 64 + rr + kk * 8;
        const size_t off = (size_t)row * 3072 + colbase + ((dgrp ^ rr) << 3);
        ushort8 vh = *(const ushort8*)&qhB[off];
        #pragma unroll
        for (int e = 0; e < 8; ++e) sacc[e] += h2f(vh[e]);
    }
    #pragma unroll
    for (int off = 8; off < 64; off <<= 1)
        #pragma unroll
        for (int e = 0; e < 8; ++e) sacc[e] += __shfl_xor(sacc[e], off);
    if (rr == 0) {
        float* dst = &tsum[((size_t)bh * 32 + t) * 64 + dgrp * 8];
        f32x4 v0, v1;
        #pragma unroll
        for (int e = 0; e < 4; ++e) { v0[e] = sacc[e]; v1[e] = sacc[4 + e]; }
        *(f32x4*)dst = v0;
        *(f32x4*)(dst + 4) = v1;
    }
}

__global__ __launch_bounds__(64) void vsuf_scan_kernel(
    const float* __restrict__ tsum, float* __restrict__ vsuf)
{
    const int bh = blockIdx.x, d = threadIdx.x;   // 32 blocks x 64 thr
    float acc = 0.f;
    vsuf[((size_t)bh * 33 + 32) * 64 + d] = 0.f;
    for (int t = 31; t >= 0; --t) {
        acc += tsum[((size_t)bh * 32 + t) * 64 + d];
        vsuf[((size_t)bh * 33 + t) * 64 + d] = acc;
    }
}

// ---------------------------------------------------------------------------
// Causal-skip MFMA flash attention, BATCH-FUSED, QBLK=64, SEGLEN=16,
// pure fp16-hi, FIXED-m=0 softmax, raw v_exp_f32 — now with K/V LDS
// DOUBLE-BUFFERING -> ONE __syncthreads() per tile (was 2):
//   LDS (shorts): K0 [0,4096) K1 [4096,8192) Vt0 [8192,12288)
//                 Vt1 [12288,16384) Pw [16384,20480)  = 40KB (4 blocks/CU).
//   Per tile t (cur=parity): issue gloadK(t+1)->K[cur^1] + vload(t+1) regs;
//   QK reads K[cur]; softmax -> per-wave Pw; vwrite(t+1)->Vt[cur^1];
//   PV reads Vt[cur]; __syncthreads() publishes K(t+1)+V(t+1).
//   All tile-t writes target buffer cur^1; reads target cur -> race-free.
// K staged via global_load_lds (pre-swizzled global, linear dest) — drops
// the kissue/kwrite register round-trip.
// grid (48, 32): x<32 = segment jobs (longest first), x>=32 direct i=47-x.
// ---------------------------------------------------------------------------
__global__ __launch_bounds__(256, 4) void attn_kernel(
    const unsigned short* __restrict__ qh,
    const float* __restrict__ vsuf,
    unsigned short* __restrict__ ohi,
    float* __restrict__ partO, float* __restrict__ partML)
{
    __shared__ __align__(16) unsigned short lds[20480];   // 40 KB

    const int tid = threadIdx.x, lane = tid & 63, w = tid >> 6;
    const int g = lane >> 4, oct = g * 8, col = lane & 15;
    const int bh = blockIdx.y;
    const int b = bh >> 4, h = bh & 15;
    const unsigned short* qhB = qh + (size_t)b * 2048 * 3072;
    const float* vsufB = vsuf + (size_t)bh * 33 * 64;
    const int brow = b * 2048;
    const int kp = tid & 31, dg = tid >> 5;

    const int job = blockIdx.x;
    int i, s = 0, slot = -1;
    if (job < 32) { const int r = job; i = 16 + (r >> 1); s = r & 1; slot = (bh << 5) + r; }
    else { i = 47 - job; }
    const int q0 = i * 64;
    const int ntile_all = i + 1;
    const int t_begin = s * 16;
    const int t_end = (slot < 0) ? ntile_all : min(t_begin + 16, ntile_all);
    const bool isseg = (slot >= 0);

    auto gloadK = [&](int ktbase, unsigned kb) {
        #pragma unroll
        for (int j = 0; j < 2; ++j) {
            const int cc = w * 2 + j;
            const int row = ktbase + cc * 8 + (lane >> 3);
            gload_lds16(qhB + (size_t)row * 3072 + h * 192 + 64 + (lane & 7) * 8,
                        &lds[kb + cc * 512]);
        }
    };
    auto vload = [&](int ktbase, f16x8& vA, f16x8& vB) {
        const int r0 = ktbase + 2 * kp, r1 = r0 + 1;
        const int pA = dg ^ (r0 & 7), pB = dg ^ (r1 & 7);
        vA = *(const f16x8*)&qhB[(size_t)r0 * 3072 + h * 192 + 128 + pA * 8];
        vB = *(const f16x8*)&qhB[(size_t)r1 * 3072 + h * 192 + 128 + pB * 8];
    };
    auto vwrite = [&](f16x8 vA, f16x8 vB, unsigned vb) {
        #pragma unroll
        for (int e = 0; e < 8; ++e) {
            const int d = dg * 8 + e;
            f16x2 pr; pr[0] = vA[e]; pr[1] = vB[e];
            *(f16x2*)&lds[vb + SWZ(d, 2 * kp)] = pr;
        }
    };

    // ---- stage Q tile (hi only) into K0 region [0,4096) shorts ----
    #pragma unroll
    for (int j = 0; j < 2; ++j) {
        const int cc = w * 2 + j;
        const int row = q0 + cc * 8 + (lane >> 3);
        gload_lds16(qhB + (size_t)row * 3072 + h * 192 + (lane & 7) * 8,
                    &lds[cc * 512]);
    }
    f16x8 vA, vB;
    vload(t_begin * 64, vA, vB);
    __syncthreads();                          // Q published
    f16x8 qfh[2];
    {
        const int qrow = w * 16 + col;
        qfh[0] = *(const f16x8*)&lds[SWZ(qrow, oct)];
        qfh[1] = *(const f16x8*)&lds[SWZ(qrow, 32 + oct)];
    }
    __syncthreads();                          // all Q reads done before K0 overwrite
    gloadK(t_begin * 64, 0u);                 // K(t_begin) -> K0
    vwrite(vA, vB, 8192u);                    // V(t_begin) -> Vt0
    __syncthreads();                          // K0 (vmcnt drain) + Vt0 published

    const int qg = q0 + w * 16 + col;
    float l_run = 0.f;                 // per-lane partial (this lane's 16 keys/tile)
    f32x4 oacc[4] = {};

    int cur = 0;
    for (int t = t_begin; t < t_end; ++t) {
        const int kt = t * 64;
        const bool pf = (t + 1 < t_end);
        const unsigned kb  = (unsigned)(cur * 4096);          // K[cur]
        const unsigned vb  = 8192u + (unsigned)(cur * 4096);  // Vt[cur]
        const unsigned kbn = (unsigned)((cur ^ 1) * 4096);
        const unsigned vbn = 8192u + (unsigned)((cur ^ 1) * 4096);

        f16x8 vA2, vB2;
        if (pf) { vload(kt + 64, vA2, vB2); gloadK(kt + 64, kbn); }

        // ---- scores: S^T[key][q] = K·Q (1-term fp16) ----
        f32x4 sacc[4] = {};
        #pragma unroll
        for (int c = 0; c < 2; ++c)
            #pragma unroll
            for (int t4 = 0; t4 < 4; ++t4) {
                const int krow = t4 * 16 + col;
                f16x8 khf = *(const f16x8*)&lds[kb + SWZ(krow, c * 32 + oct)];
                sacc[t4] = mfma16(khf, qfh[c], sacc[t4]);
            }

        // ---- softmax, fixed m=0: raw v_exp_f32 + pack + accumulate ----
        unsigned short* Pw = &lds[16384 + w * 1024];
        if (t == ntile_all - 1) {   // diagonal tile: masked logit -> weight 1
            #pragma unroll
            for (int t4 = 0; t4 < 4; ++t4)
                #pragma unroll
                for (int rp = 0; rp < 2; ++rp) {
                    const int k0 = kt + t4 * 16 + g * 4 + rp * 2;
                    float s0 = sacc[t4][rp * 2]     * EXPSC;
                    float s1 = sacc[t4][rp * 2 + 1] * EXPSC;
                    if (k0 > qg)     s0 = 0.0f;
                    if (k0 + 1 > qg) s1 = 0.0f;
                    float e0 = EXP2R(s0), e1 = EXP2R(s1);
                    l_run += e0 + e1;
                    f16x2 pk; pk[0] = (_Float16)e0; pk[1] = (_Float16)e1;
                    *(f16x2*)&Pw[SWZ(col, t4 * 16 + g * 4 + rp * 2)] = pk;
                }
        } else {
            #pragma unroll
            for (int t4 = 0; t4 < 4; ++t4)
                #pragma unroll
                for (int rp = 0; rp < 2; ++rp) {
                    float e0 = EXP2R(sacc[t4][rp * 2]     * EXPSC);
                    float e1 = EXP2R(sacc[t4][rp * 2 + 1] * EXPSC);
                    l_run += e0 + e1;
                    f16x2 pk; pk[0] = (_Float16)e0; pk[1] = (_Float16)e1;
                    *(f16x2*)&Pw[SWZ(col, t4 * 16 + g * 4 + rp * 2)] = pk;
                }
        }

        // V(t+1) -> other buffer (no barrier needed; PV below reads cur buffer)
        if (pf) vwrite(vA2, vB2, vbn);

        __builtin_amdgcn_wave_barrier();      // pin own Pw writes before reads

        // ---- PV: O^T[d][q] += Vt · P (no rescale; m fixed) ----
        #pragma unroll
        for (int c = 0; c < 2; ++c) {
            f16x8 pfv = *(const f16x8*)&Pw[SWZ(col, c * 32 + oct)];
            #pragma unroll
            for (int dt = 0; dt < 4; ++dt) {
                f16x8 vh = *(const f16x8*)&lds[vb + SWZ(dt * 16 + col, c * 32 + oct)];
                oacc[dt] = mfma16(vh, pfv, oacc[dt]);
            }
        }

        __syncthreads();                      // publish K(t+1) + Vt(t+1); all reads done
        cur ^= 1;
    }

    // ---- reduce l across the 4 key-groups (once, not per tile) ----
    float lt = l_run;
    lt += __shfl_xor(lt, 16);
    lt += __shfl_xor(lt, 32);

    if (isseg) {
        float* po = partO + (size_t)slot * 4096;
        #pragma unroll
        for (int dt = 0; dt < 4; ++dt)
            #pragma unroll
            for (int r = 0; r < 4; ++r)
                po[(dt * 16 + g * 4 + r) * 64 + w * 16 + col] = oacc[dt][r];
        if (g == 0) partML[(size_t)slot * 128 + w * 16 + col] = lt;
        return;
    }

    // ---- direct: masked tail weight = 1 per key, exact ----
    lt += (float)(S_ - q0 - 64);
    {
        const float* vs = vsufB + (size_t)(i + 1) * 64;
        #pragma unroll
        for (int dt = 0; dt < 4; ++dt)
            #pragma unroll
            for (int r = 0; r < 4; ++r)
                oacc[dt][r] += vs[dt * 16 + g * 4 + r];
    }
    const float inv = 1.f / lt;
    float* ow = (float*)&lds[w * 4096];
    const int q = lane >> 2, jj = lane & 3;
    #pragma unroll
    for (int half = 0; half < 2; ++half) {
        __builtin_amdgcn_wave_barrier();
        #pragma unroll
        for (int t4 = 0; t4 < 2; ++t4)
            #pragma unroll
            for (int r = 0; r < 4; ++r)
                ow[col * 40 + t4 * 16 + g * 4 + r] = oacc[half * 2 + t4][r] * inv;
        __builtin_amdgcn_wave_barrier();
        f32x4 v0 = *(const f32x4*)&ow[q * 40 + jj * 8];
        f32x4 v1 = *(const f32x4*)&ow[q * 40 + jj * 8 + 4];
        ushort8 hi = pack2x4h(v0, v1);
        const int m = brow + q0 + w * 16 + q;
        const int chunk = (half * 4 + jj) ^ (m & 7);
        *(ushort8*)&ohi[(size_t)m * 1024 + h * 64 + chunk * 8] = hi;
    }
}

// ---------------------------------------------------------------------------
// Combine partials for split q-tiles (i>=16), batched: grid (16, 32).
// Fixed m=0: lstar = sum l + tailcount, od = sum O + vsuf.
// ---------------------------------------------------------------------------
__global__ __launch_bounds__(256) void attn_combine_kernel(
    const float* __restrict__ partO, const float* __restrict__ partML,
    const float* __restrict__ vsuf,
    unsigned short* __restrict__ ohi)
{
    const int i = 16 + blockIdx.x;              // 16..31
    const int bh = blockIdx.y;
    const int b = bh >> 4, h = bh & 15;
    const float* vsufB = vsuf + (size_t)bh * 33 * 64;
    const int brow = b * 2048;
    const int nseg = 2;
    const int slot0 = (bh << 5) + (i - 16) * 2;
    const int q = threadIdx.x & 63, dgrp = threadIdx.x >> 6;
    const int q0 = i * 64;

    float lstar = (float)(S_ - q0 - 64);        // masked tail, weight 1 each

    float od[16];
    const float* vs = vsufB + (size_t)(i + 1) * 64 + dgrp * 16;
    #pragma unroll
    for (int k = 0; k < 16; ++k) od[k] = vs[k];

    for (int sg = 0; sg < nseg; ++sg) {
        lstar += partML[(size_t)(slot0 + sg) * 128 + q];
        const float* po = partO + (size_t)(slot0 + sg) * 4096 + (size_t)(dgrp * 16) * 64 + q;
        #pragma unroll
        for (int k = 0; k < 16; ++k) od[k] += po[k * 64];
    }

    const float inv = 1.f / lstar;
    f32x4 a0, a1, b0, b1;
    #pragma unroll
    for (int k = 0; k < 4; ++k) {
        a0[k] = od[k] * inv; a1[k] = od[4 + k] * inv;
        b0[k] = od[8 + k] * inv; b1[k] = od[12 + k] * inv;
    }
    ushort8 hi0 = pack2x4h(a0, a1);
    ushort8 hi1 = pack2x4h(b0, b1);
    const int mrow = brow + q0 + q;
    const int c0 = (dgrp * 2) ^ (mrow & 7);
    const int c1 = (dgrp * 2 + 1) ^ (mrow & 7);
    const size_t base = (size_t)mrow * 1024 + h * 64;
    *(ushort8*)&ohi[base + c0 * 8] = hi0;
    *(ushort8*)&ohi[base + c1 * 8] = hi1;
}

// ---------------------------------------------------------------------------
extern "C" void kernel_launch(void* const* d_in, const int* in_sizes, int n_in,
                              void* d_out, int out_size, void* d_ws, size_t ws_size,
                              hipStream_t stream) {
    const float* x     = (const float*)d_in[0];   // [B,S,D]
    const float* W_qkv = (const float*)d_in[1];   // [D,3D]
    const float* b_qkv = (const float*)d_in[2];   // [3D]
    const float* W_out = (const float*)d_in[3];   // [D,D]
    const float* b_out = (const float*)d_in[4];   // [D]
    float* out = (float*)d_out;                   // [B,S,D]

    // ws layout (~42.5 MB; hi-only everywhere)
    unsigned short* us  = (unsigned short*)d_ws;
    unsigned short* Wqh = us;                                  // [3072][1024]
    unsigned short* Woh = Wqh + (size_t)3072 * 1024;           // [1024][1024]
    unsigned short* XAhi = Woh + (size_t)1024 * 1024;          // [4096][1024] X, then attn-out
    unsigned short* QKVh = XAhi + (size_t)4096 * 1024;         // [4096][3072]
    float* tsum   = (float*)(QKVh + (size_t)4096 * 3072);      // [32][32][64]
    float* vsuf   = tsum + (size_t)32 * 32 * 64;               // [32][33][64]
    float* partML = vsuf + (size_t)32 * 33 * 64;               // [1024][128]

    float* partO = out;                        // [1024][4096] = exactly d_out
    float* p1    = (float*)QKVh;               // split-K half-1 (dead after attn)

    conv_wt_kernel<<<dim3(16, 64), 256, 0, stream>>>(W_qkv, W_out, Wqh, Woh);
    conv_rows_kernel<<<dim3(2048), 256, 0, stream>>>(x, XAhi);

    // fused-batch QKV projection (pure fp16): grid 768 = 3 blocks/CU
    gemm16_kernel<1><<<dim3(24, 32), 256, 0, stream>>>(
        XAhi, Wqh, b_qkv, nullptr, nullptr, QKVh, 4096, 3072, 1024);

    // batched V-suffix sums (hi-only)
    vsuf_part_kernel<<<dim3(32, 8), 256, 0, stream>>>(QKVh, tsum);
    vsuf_scan_kernel<<<dim3(32), 64, 0, stream>>>(tsum, vsuf);

    // batch-fused attention (K/V double-buffered, 1 barrier/tile) + combine
    attn_kernel<<<dim3(48, 32), 256, 0, stream>>>(
        QKVh, vsuf, XAhi, partO, partML);
    attn_combine_kernel<<<dim3(16, 32), 256, 0, stream>>>(
        partO, partML, vsuf, XAhi);

    // split-K output projection + combine
    gemm16_kernel<2><<<dim3(8, 64), 256, 0, stream>>>(
        XAhi, Woh, b_out, out, p1, nullptr, 4096, 1024, 512);
    addp_kernel<<<dim3(4096), 256, 0, stream>>>(out, p1);
}

// Round 22
// 127.655 us; speedup vs baseline: 1.0437x; 1.0437x over previous
//
#include <hip/hip_runtime.h>
#include <math.h>

// Problem constants (reference: B=2, S=2048, D=1024, H=16, HD=64)
#define B_ 2
#define S_ 2048
#define D_ 1024
#define H_ 16
#define HD_ 64

typedef unsigned short ushort8 __attribute__((ext_vector_type(8)));
typedef unsigned int u32x4 __attribute__((ext_vector_type(4)));
typedef _Float16 f16x8 __attribute__((ext_vector_type(8)));
typedef _Float16 f16x2 __attribute__((ext_vector_type(2)));
typedef float f32x4 __attribute__((ext_vector_type(4)));

__device__ __forceinline__ unsigned short f2h(float f) {
    union { _Float16 h; unsigned short u; } v;
    v.h = (_Float16)f;                     // native v_cvt_f16_f32, RNE
    return v.u;
}
__device__ __forceinline__ float h2f(unsigned short u) {
    union { unsigned short u; _Float16 h; } v; v.u = u;
    return (float)v.h;
}
__device__ __forceinline__ ushort8 pack2x4h(f32x4 a, f32x4 b) {
    ushort8 hi;
    #pragma unroll
    for (int i = 0; i < 4; ++i) { hi[i] = f2h(a[i]); hi[4 + i] = f2h(b[i]); }
    return hi;
}

// XOR swizzle for [R][64] f16 tiles (128B rows): in-row 16B-chunk permute by row&7.
#define SWZ(row, col) ((((row)) << 6) + (((col)) ^ ((((row)) & 7) << 3)))

__device__ __forceinline__ f32x4 mfma16(f16x8 a, f16x8 b, f32x4 c) {
    return __builtin_amdgcn_mfma_f32_16x16x32_f16(a, b, c, 0, 0, 0);
}

typedef __attribute__((address_space(1))) const void gvoid_t;
typedef __attribute__((address_space(3))) void lvoid_t;
typedef __attribute__((address_space(3))) unsigned short lds_us_t;
__device__ __forceinline__ void gload_lds16(const void* g, void* l) {
    __builtin_amdgcn_global_load_lds((gvoid_t*)g, (lvoid_t*)l, 16, 0, 0);
}
// inline-asm LDS read: opaque to the compiler's waitcnt pass (counted vmcnt survives)
__device__ __forceinline__ f16x8 dsr128(unsigned addr) {
    u32x4 r;
    asm volatile("ds_read_b128 %0, %1" : "=v"(r) : "v"(addr));
    union { u32x4 u; f16x8 h; } cv; cv.u = r; return cv.h;
}

// exp(s*0.125) == 2^(s * 0.125*log2e); raw v_exp_f32 (natively 2^x, no libm tail).
#define EXPSC 0.18033688011f
#define EXP2R(x) __builtin_amdgcn_exp2f(x)

// ---------------------------------------------------------------------------
// conv_rows: fp32 [4096][1024] -> fp16 hi, pre-swizzled (key = row&7)
// ---------------------------------------------------------------------------
__global__ __launch_bounds__(256) void conv_rows_kernel(
    const float* __restrict__ in, unsigned short* __restrict__ ohi)
{
    const int id = blockIdx.x * 256 + threadIdx.x;   // [0, 4096*128)
    const int r = id >> 7, c = id & 127;
    const float* s = in + (size_t)r * 1024 + c * 8;
    f32x4 v0 = *(const f32x4*)s, v1 = *(const f32x4*)(s + 4);
    ushort8 hi = pack2x4h(v0, v1);
    const int oc = (c & ~7) | ((c ^ r) & 7);
    *(ushort8*)&ohi[(size_t)r * 1024 + oc * 8] = hi;
}

// ---------------------------------------------------------------------------
// conv_wt (merged, hi-only): grid (16, 64): y<48 -> W_qkv (ldw 3072), else
// W_out (ldw 1024). fp32 -> Wt fp16 hi [N][1024], transposed + pre-swizzled.
// ---------------------------------------------------------------------------
__global__ __launch_bounds__(256) void conv_wt_kernel(
    const float* __restrict__ Wq, const float* __restrict__ Wo,
    unsigned short* __restrict__ Wqh, unsigned short* __restrict__ Woh)
{
    __shared__ float T[64][65];
    const float* W; int ldw, ny;
    unsigned short *oh;
    if (blockIdx.y < 48) { W = Wq; ldw = 3072; ny = blockIdx.y * 64; oh = Wqh; }
    else                 { W = Wo; ldw = 1024; ny = (blockIdx.y - 48) * 64; oh = Woh; }
    const int tid = threadIdx.x;
    const int kx = blockIdx.x * 64;
    const int kl = tid >> 2, c0 = (tid & 3) * 16;
    const float* s = W + (size_t)(kx + kl) * ldw + ny + c0;
    #pragma unroll
    for (int i = 0; i < 4; ++i) *(f32x4*)&T[kl][c0 + 4 * i] = *(const f32x4*)(s + 4 * i);
    __syncthreads();
    const int nl = tid >> 2, jj = (tid & 3) * 2;
    #pragma unroll
    for (int p = 0; p < 2; ++p) {
        const int j = jj + p;
        f32x4 a, b;
        #pragma unroll
        for (int i = 0; i < 4; ++i) a[i] = T[j * 8 + i][nl];
        #pragma unroll
        for (int i = 0; i < 4; ++i) b[i] = T[j * 8 + 4 + i][nl];
        ushort8 hi = pack2x4h(a, b);
        const int row = ny + nl;
        const int chunk = blockIdx.x * 8 + (j ^ (nl & 7));
        *(ushort8*)&oh[(size_t)row * 1024 + chunk * 8] = hi;
    }
}

// ---------------------------------------------------------------------------
// Pure fp16 MFMA GEMM (1-term, r16-r21 proven): C = Ah @ Bth^T (+ bias).
// 128x128 tile, BK=32, 2 x 16KB LDS dbuf, 4 blocks/CU, counted vmcnt(4).
// OUTMODE 1: fp16 hi out (+bias). OUTMODE 2: split-K fp32.
// ---------------------------------------------------------------------------
template<int OUTMODE>
__global__ __launch_bounds__(256, 4) void gemm16_kernel(
    const unsigned short* __restrict__ Ah, const unsigned short* __restrict__ Bth,
    const float* __restrict__ bias, float* __restrict__ Cf, float* __restrict__ Cf1,
    unsigned short* __restrict__ Ohi,
    int M, int N, int K)
{
    __shared__ __align__(16) unsigned short lds[16384];   // 32KB: 2 x 16KB buffers

    const int tid = threadIdx.x, lane = tid & 63, w = tid >> 6;
    const int wm = w >> 1, wn = w & 1;
    const int gx = gridDim.x, nwg = gx * gridDim.y;
    const int lin = blockIdx.y * gx + blockIdx.x;
    const int nl = (lin & 7) * (nwg >> 3) + (lin >> 3);
    int mblk = nl / gx;
    int koff = 0;
    float* Cfw = Cf;
    bool dobias = (OUTMODE != 2);
    if (OUTMODE == 2) {
        const int halfrows = (int)(gridDim.y >> 1);
        if (mblk >= halfrows) { mblk -= halfrows; koff = 512; Cfw = Cf1; dobias = false; }
        else dobias = true;
    }
    const int m0 = mblk * 128, n0 = (nl % gx) * 128;
    const int col = lane & 15, g = lane >> 4;
    const int NT = K >> 5;

    const int sr0 = (w * 2 + 0) * 16 + (lane >> 2);
    const int sr1 = (w * 2 + 1) * 16 + (lane >> 2);
    const int scp = lane & 3;

    auto stage = [&](int tt) {
        unsigned short* dst = &lds[(tt & 1) * 8192];
        const int hi8 = (tt >> 1) * 8;
        const int tb4 = (tt & 1) << 2;
        #pragma unroll
        for (int q = 0; q < 2; ++q) {
            const int r = q ? sr1 : sr0;
            const int p = hi8 + ((tb4 ^ (r & 4)) | (scp ^ ((r >> 2) & 3)));
            const size_t go = (size_t)p * 8 + koff;
            const int slotb = (w * 2 + q) * 512;
            gload_lds16(Ah  + (size_t)(m0 + r) * 1024 + go, dst + 0    + slotb);
            gload_lds16(Bth + (size_t)(n0 + r) * 1024 + go, dst + 4096 + slotb);
        }
    };

    const unsigned ldsb = (unsigned)(size_t)(lds_us_t*)lds;
    const unsigned sk = (unsigned)(((g ^ (col & 3) ^ ((col >> 2) & 3)) & 3) << 4);
    const unsigned aB = ldsb + (unsigned)((wm * 64 + col) * 64) + sk;
    const unsigned bB = ldsb + 8192u + (unsigned)((wn * 64 + col) * 64) + sk;

    f32x4 acc[4][4] = {};

    stage(0);
    stage(1);

    for (int tt = 0; tt < NT; ++tt) {
        if (tt + 1 < NT) asm volatile("s_waitcnt vmcnt(4)" ::: "memory");
        else             asm volatile("s_waitcnt vmcnt(0)" ::: "memory");
        __builtin_amdgcn_s_barrier();
        __builtin_amdgcn_sched_barrier(0);
        const unsigned bo = (unsigned)((tt & 1) * 16384);

        f16x8 a[4], b[4];
        #pragma unroll
        for (int i = 0; i < 4; ++i) a[i] = dsr128(aB + bo + i * 1024u);
        #pragma unroll
        for (int i = 0; i < 4; ++i) b[i] = dsr128(bB + bo + i * 1024u);

        asm volatile("s_waitcnt lgkmcnt(0)" ::: "memory");
        __builtin_amdgcn_sched_barrier(0);
        __builtin_amdgcn_s_setprio(1);
        #pragma unroll
        for (int mi = 0; mi < 4; ++mi)
            #pragma unroll
            for (int nj = 0; nj < 4; ++nj)
                acc[mi][nj] = mfma16(a[mi], b[nj], acc[mi][nj]);
        __builtin_amdgcn_s_setprio(0);
        __builtin_amdgcn_s_barrier();
        __builtin_amdgcn_sched_barrier(0);
        if (tt + 2 < NT) stage(tt + 2);
    }

    // ---- epilogue: per-wave LDS transpose in two 32-row halves ----
    __syncthreads();
    float* ow = (float*)((char*)lds + w * 8192);   // [32][64] fp32 per wave
    const int nc = (lane & 7) * 8;
    const int nabs = n0 + wn * 64 + nc;
    f32x4 bi0 = {}, bi1 = {};
    if (dobias) { bi0 = *(const f32x4*)&bias[nabs]; bi1 = *(const f32x4*)&bias[nabs + 4]; }
    #pragma unroll
    for (int half = 0; half < 2; ++half) {
        __builtin_amdgcn_wave_barrier();
        #pragma unroll
        for (int ml = 0; ml < 2; ++ml)
            #pragma unroll
            for (int nj = 0; nj < 4; ++nj)
                #pragma unroll
                for (int r = 0; r < 4; ++r)
                    ow[(ml * 16 + g * 4 + r) * 64 + nj * 16 + col] = acc[half * 2 + ml][nj][r];
        __builtin_amdgcn_wave_barrier();
        #pragma unroll
        for (int it = 0; it < 4; ++it) {
            const int rl = it * 8 + (lane >> 3);
            f32x4 v0 = *(const f32x4*)&ow[rl * 64 + nc];
            f32x4 v1 = *(const f32x4*)&ow[rl * 64 + nc + 4];
            if (dobias) { v0 += bi0; v1 += bi1; }
            const int m = m0 + wm * 64 + half * 32 + rl;
            if (OUTMODE == 1) {
                ushort8 hi = pack2x4h(v0, v1);
                const int chunk = (lane & 7) ^ (m & 7);
                *(ushort8*)&Ohi[(size_t)m * N + n0 + wn * 64 + chunk * 8] = hi;
            } else {
                *(f32x4*)&Cfw[(size_t)m * N + nabs] = v0;
                *(f32x4*)&Cfw[(size_t)m * N + nabs + 4] = v1;
            }
        }
        __builtin_amdgcn_wave_barrier();
    }
}

// ---------------------------------------------------------------------------
// out += p1   (split-K combine)
// ---------------------------------------------------------------------------
__global__ __launch_bounds__(256) void addp_kernel(
    float* __restrict__ out, const float* __restrict__ p1)
{
    const size_t idx = ((size_t)blockIdx.x * 256 + threadIdx.x) * 4;
    f32x4 v = *(const f32x4*)&out[idx];
    f32x4 u = *(const f32x4*)&p1[idx];
    v += u;
    *(f32x4*)&out[idx] = v;
}

// ---------------------------------------------------------------------------
// V suffix tile sums (hi-only), batched: grid (32, 8); blockIdx.x = b*16+h
// ---------------------------------------------------------------------------
__global__ __launch_bounds__(256) void vsuf_part_kernel(
    const unsigned short* __restrict__ qh, float* __restrict__ tsum)
{
    const int bh = blockIdx.x, tg = blockIdx.y;
    const int b = bh >> 4, h = bh & 15;
    const unsigned short* qhB = qh + (size_t)b * 2048 * 3072;
    const int tl = threadIdx.x >> 6, lane = threadIdx.x & 63;
    const int t = tg * 4 + tl;
    const int dgrp = lane & 7, rr = lane >> 3;
    const int colbase = h * 192 + 128;
    float sacc[8] = {};
    for (int kk = 0; kk < 8; ++kk) {
        const int row = t * 64 + rr + kk * 8;
        const size_t off = (size_t)row * 3072 + colbase + ((dgrp ^ rr) << 3);
        ushort8 vh = *(const ushort8*)&qhB[off];
        #pragma unroll
        for (int e = 0; e < 8; ++e) sacc[e] += h2f(vh[e]);
    }
    #pragma unroll
    for (int off = 8; off < 64; off <<= 1)
        #pragma unroll
        for (int e = 0; e < 8; ++e) sacc[e] += __shfl_xor(sacc[e], off);
    if (rr == 0) {
        float* dst = &tsum[((size_t)bh * 32 + t) * 64 + dgrp * 8];
        f32x4 v0, v1;
        #pragma unroll
        for (int e = 0; e < 4; ++e) { v0[e] = sacc[e]; v1[e] = sacc[4 + e]; }
        *(f32x4*)dst = v0;
        *(f32x4*)(dst + 4) = v1;
    }
}

__global__ __launch_bounds__(64) void vsuf_scan_kernel(
    const float* __restrict__ tsum, float* __restrict__ vsuf)
{
    const int bh = blockIdx.x, d = threadIdx.x;   // 32 blocks x 64 thr
    float acc = 0.f;
    vsuf[((size_t)bh * 33 + 32) * 64 + d] = 0.f;
    for (int t = 31; t >= 0; --t) {
        acc += tsum[((size_t)bh * 32 + t) * 64 + d];
        vsuf[((size_t)bh * 33 + t) * 64 + d] = acc;
    }
}

// ---------------------------------------------------------------------------
// Causal-skip MFMA flash attention, BATCH-FUSED, QBLK=64, SEGLEN=10 (r22:
// max job 16->10 tiles; r21 counters showed occupancy-decay tail: 23% occ,
// wall ~ longest-job x per-tile). Partials now live in WS (30.4MB free).
// Per bh: jobs 0..57 = segments of q-tiles i>=10 (r4-proven decode, <=10
// tiles each); jobs 58..67 = direct i = 67-job (9..0). grid (68, 32).
// K/V LDS double-buffered, 1 barrier/tile (r21). Fixed-m=0 softmax, v_exp.
// ---------------------------------------------------------------------------
__global__ __launch_bounds__(256, 4) void attn_kernel(
    const unsigned short* __restrict__ qh,
    const float* __restrict__ vsuf,
    unsigned short* __restrict__ ohi,
    float* __restrict__ partO, float* __restrict__ partML)
{
    __shared__ __align__(16) unsigned short lds[20480];   // 40 KB

    const int tid = threadIdx.x, lane = tid & 63, w = tid >> 6;
    const int g = lane >> 4, oct = g * 8, col = lane & 15;
    const int bh = blockIdx.y;
    const int b = bh >> 4, h = bh & 15;
    const unsigned short* qhB = qh + (size_t)b * 2048 * 3072;
    const float* vsufB = vsuf + (size_t)bh * 33 * 64;
    const int brow = b * 2048;
    const int kp = tid & 31, dg = tid >> 5;

    const int job = blockIdx.x;
    int i = 0, s = 0, slot = -1;
    if (job < 58) {
        int r = job, cum = 0;
        for (int ii = 10; ii < 32; ++ii) {
            const int ns = (ii + 10) / 10;
            if (r < cum + ns) { i = ii; s = r - cum; break; }
            cum += ns;
        }
        slot = bh * 58 + job;
    } else {
        i = 67 - job;                  // 9..0
    }
    const int q0 = i * 64;
    const int ntile_all = i + 1;
    const int t_begin = s * 10;
    const int t_end = (slot < 0) ? ntile_all : min(t_begin + 10, ntile_all);
    const bool isseg = (slot >= 0);

    auto gloadK = [&](int ktbase, unsigned kb) {
        #pragma unroll
        for (int j = 0; j < 2; ++j) {
            const int cc = w * 2 + j;
            const int row = ktbase + cc * 8 + (lane >> 3);
            gload_lds16(qhB + (size_t)row * 3072 + h * 192 + 64 + (lane & 7) * 8,
                        &lds[kb + cc * 512]);
        }
    };
    auto vload = [&](int ktbase, f16x8& vA, f16x8& vB) {
        const int r0 = ktbase + 2 * kp, r1 = r0 + 1;
        const int pA = dg ^ (r0 & 7), pB = dg ^ (r1 & 7);
        vA = *(const f16x8*)&qhB[(size_t)r0 * 3072 + h * 192 + 128 + pA * 8];
        vB = *(const f16x8*)&qhB[(size_t)r1 * 3072 + h * 192 + 128 + pB * 8];
    };
    auto vwrite = [&](f16x8 vA, f16x8 vB, unsigned vb) {
        #pragma unroll
        for (int e = 0; e < 8; ++e) {
            const int d = dg * 8 + e;
            f16x2 pr; pr[0] = vA[e]; pr[1] = vB[e];
            *(f16x2*)&lds[vb + SWZ(d, 2 * kp)] = pr;
        }
    };

    // ---- stage Q tile (hi only) into K0 region [0,4096) shorts ----
    #pragma unroll
    for (int j = 0; j < 2; ++j) {
        const int cc = w * 2 + j;
        const int row = q0 + cc * 8 + (lane >> 3);
        gload_lds16(qhB + (size_t)row * 3072 + h * 192 + (lane & 7) * 8,
                    &lds[cc * 512]);
    }
    f16x8 vA, vB;
    vload(t_begin * 64, vA, vB);
    __syncthreads();                          // Q published
    f16x8 qfh[2];
    {
        const int qrow = w * 16 + col;
        qfh[0] = *(const f16x8*)&lds[SWZ(qrow, oct)];
        qfh[1] = *(const f16x8*)&lds[SWZ(qrow, 32 + oct)];
    }
    __syncthreads();                          // all Q reads done before K0 overwrite
    gloadK(t_begin * 64, 0u);                 // K(t_begin) -> K0
    vwrite(vA, vB, 8192u);                    // V(t_begin) -> Vt0
    __syncthreads();                          // K0 (vmcnt drain) + Vt0 published

    const int qg = q0 + w * 16 + col;
    float l_run = 0.f;                 // per-lane partial (this lane's 16 keys/tile)
    f32x4 oacc[4] = {};

    int cur = 0;
    for (int t = t_begin; t < t_end; ++t) {
        const int kt = t * 64;
        const bool pf = (t + 1 < t_end);
        const unsigned kb  = (unsigned)(cur * 4096);          // K[cur]
        const unsigned vb  = 8192u + (unsigned)(cur * 4096);  // Vt[cur]
        const unsigned kbn = (unsigned)((cur ^ 1) * 4096);
        const unsigned vbn = 8192u + (unsigned)((cur ^ 1) * 4096);

        f16x8 vA2, vB2;
        if (pf) { vload(kt + 64, vA2, vB2); gloadK(kt + 64, kbn); }

        // ---- scores: S^T[key][q] = K·Q (1-term fp16) ----
        f32x4 sacc[4] = {};
        #pragma unroll
        for (int c = 0; c < 2; ++c)
            #pragma unroll
            for (int t4 = 0; t4 < 4; ++t4) {
                const int krow = t4 * 16 + col;
                f16x8 khf = *(const f16x8*)&lds[kb + SWZ(krow, c * 32 + oct)];
                sacc[t4] = mfma16(khf, qfh[c], sacc[t4]);
            }

        // ---- softmax, fixed m=0: raw v_exp_f32 + pack + accumulate ----
        unsigned short* Pw = &lds[16384 + w * 1024];
        if (t == ntile_all - 1) {   // diagonal tile: masked logit -> weight 1
            #pragma unroll
            for (int t4 = 0; t4 < 4; ++t4)
                #pragma unroll
                for (int rp = 0; rp < 2; ++rp) {
                    const int k0 = kt + t4 * 16 + g * 4 + rp * 2;
                    float s0 = sacc[t4][rp * 2]     * EXPSC;
                    float s1 = sacc[t4][rp * 2 + 1] * EXPSC;
                    if (k0 > qg)     s0 = 0.0f;
                    if (k0 + 1 > qg) s1 = 0.0f;
                    float e0 = EXP2R(s0), e1 = EXP2R(s1);
                    l_run += e0 + e1;
                    f16x2 pk; pk[0] = (_Float16)e0; pk[1] = (_Float16)e1;
                    *(f16x2*)&Pw[SWZ(col, t4 * 16 + g * 4 + rp * 2)] = pk;
                }
        } else {
            #pragma unroll
            for (int t4 = 0; t4 < 4; ++t4)
                #pragma unroll
                for (int rp = 0; rp < 2; ++rp) {
                    float e0 = EXP2R(sacc[t4][rp * 2]     * EXPSC);
                    float e1 = EXP2R(sacc[t4][rp * 2 + 1] * EXPSC);
                    l_run += e0 + e1;
                    f16x2 pk; pk[0] = (_Float16)e0; pk[1] = (_Float16)e1;
                    *(f16x2*)&Pw[SWZ(col, t4 * 16 + g * 4 + rp * 2)] = pk;
                }
        }

        // V(t+1) -> other buffer (no barrier needed; PV below reads cur buffer)
        if (pf) vwrite(vA2, vB2, vbn);

        __builtin_amdgcn_wave_barrier();      // pin own Pw writes before reads

        // ---- PV: O^T[d][q] += Vt · P (no rescale; m fixed) ----
        #pragma unroll
        for (int c = 0; c < 2; ++c) {
            f16x8 pfv = *(const f16x8*)&Pw[SWZ(col, c * 32 + oct)];
            #pragma unroll
            for (int dt = 0; dt < 4; ++dt) {
                f16x8 vh = *(const f16x8*)&lds[vb + SWZ(dt * 16 + col, c * 32 + oct)];
                oacc[dt] = mfma16(vh, pfv, oacc[dt]);
            }
        }

        __syncthreads();                      // publish K(t+1) + Vt(t+1); all reads done
        cur ^= 1;
    }

    // ---- reduce l across the 4 key-groups (once, not per tile) ----
    float lt = l_run;
    lt += __shfl_xor(lt, 16);
    lt += __shfl_xor(lt, 32);

    if (isseg) {
        float* po = partO + (size_t)slot * 4096;
        #pragma unroll
        for (int dt = 0; dt < 4; ++dt)
            #pragma unroll
            for (int r = 0; r < 4; ++r)
                po[(dt * 16 + g * 4 + r) * 64 + w * 16 + col] = oacc[dt][r];
        if (g == 0) partML[(size_t)slot * 128 + w * 16 + col] = lt;
        return;
    }

    // ---- direct: masked tail weight = 1 per key, exact ----
    lt += (float)(S_ - q0 - 64);
    {
        const float* vs = vsufB + (size_t)(i + 1) * 64;
        #pragma unroll
        for (int dt = 0; dt < 4; ++dt)
            #pragma unroll
            for (int r = 0; r < 4; ++r)
                oacc[dt][r] += vs[dt * 16 + g * 4 + r];
    }
    const float inv = 1.f / lt;
    float* ow = (float*)&lds[w * 4096];
    const int q = lane >> 2, jj = lane & 3;
    #pragma unroll
    for (int half = 0; half < 2; ++half) {
        __builtin_amdgcn_wave_barrier();
        #pragma unroll
        for (int t4 = 0; t4 < 2; ++t4)
            #pragma unroll
            for (int r = 0; r < 4; ++r)
                ow[col * 40 + t4 * 16 + g * 4 + r] = oacc[half * 2 + t4][r] * inv;
        __builtin_amdgcn_wave_barrier();
        f32x4 v0 = *(const f32x4*)&ow[q * 40 + jj * 8];
        f32x4 v1 = *(const f32x4*)&ow[q * 40 + jj * 8 + 4];
        ushort8 hi = pack2x4h(v0, v1);
        const int m = brow + q0 + w * 16 + q;
        const int chunk = (half * 4 + jj) ^ (m & 7);
        *(ushort8*)&ohi[(size_t)m * 1024 + h * 64 + chunk * 8] = hi;
    }
}

// ---------------------------------------------------------------------------
// Combine partials for split q-tiles (i>=10), batched: grid (22, 32).
// Fixed m=0: lstar = sum l + tailcount, od = sum O + vsuf. nseg = 2..4.
// ---------------------------------------------------------------------------
__global__ __launch_bounds__(256) void attn_combine_kernel(
    const float* __restrict__ partO, const float* __restrict__ partML,
    const float* __restrict__ vsuf,
    unsigned short* __restrict__ ohi)
{
    const int i = 10 + blockIdx.x;              // 10..31
    const int bh = blockIdx.y;
    const int b = bh >> 4, h = bh & 15;
    const float* vsufB = vsuf + (size_t)bh * 33 * 64;
    const int brow = b * 2048;
    const int nseg = (i + 10) / 10;
    int cum = 0;
    for (int j = 10; j < i; ++j) cum += (j + 10) / 10;
    const int slot0 = bh * 58 + cum;
    const int q = threadIdx.x & 63, dgrp = threadIdx.x >> 6;
    const int q0 = i * 64;

    float lstar = (float)(S_ - q0 - 64);        // masked tail, weight 1 each

    float od[16];
    const float* vs = vsufB + (size_t)(i + 1) * 64 + dgrp * 16;
    #pragma unroll
    for (int k = 0; k < 16; ++k) od[k] = vs[k];

    for (int sg = 0; sg < nseg; ++sg) {
        lstar += partML[(size_t)(slot0 + sg) * 128 + q];
        const float* po = partO + (size_t)(slot0 + sg) * 4096 + (size_t)(dgrp * 16) * 64 + q;
        #pragma unroll
        for (int k = 0; k < 16; ++k) od[k] += po[k * 64];
    }

    const float inv = 1.f / lstar;
    f32x4 a0, a1, b0, b1;
    #pragma unroll
    for (int k = 0; k < 4; ++k) {
        a0[k] = od[k] * inv; a1[k] = od[4 + k] * inv;
        b0[k] = od[8 + k] * inv; b1[k] = od[12 + k] * inv;
    }
    ushort8 hi0 = pack2x4h(a0, a1);
    ushort8 hi1 = pack2x4h(b0, b1);
    const int mrow = brow + q0 + q;
    const int c0 = (dgrp * 2) ^ (mrow & 7);
    const int c1 = (dgrp * 2 + 1) ^ (mrow & 7);
    const size_t base = (size_t)mrow * 1024 + h * 64;
    *(ushort8*)&ohi[base + c0 * 8] = hi0;
    *(ushort8*)&ohi[base + c1 * 8] = hi1;
}

// ---------------------------------------------------------------------------
extern "C" void kernel_launch(void* const* d_in, const int* in_sizes, int n_in,
                              void* d_out, int out_size, void* d_ws, size_t ws_size,
                              hipStream_t stream) {
    const float* x     = (const float*)d_in[0];   // [B,S,D]
    const float* W_qkv = (const float*)d_in[1];   // [D,3D]
    const float* b_qkv = (const float*)d_in[2];   // [3D]
    const float* W_out = (const float*)d_in[3];   // [D,D]
    const float* b_out = (const float*)d_in[4];   // [D]
    float* out = (float*)d_out;                   // [B,S,D]

    // ws layout (~74 MB; >= 84.2 MB proven since r8)
    unsigned short* us  = (unsigned short*)d_ws;
    unsigned short* Wqh = us;                                  // [3072][1024]
    unsigned short* Woh = Wqh + (size_t)3072 * 1024;           // [1024][1024]
    unsigned short* XAhi = Woh + (size_t)1024 * 1024;          // [4096][1024] X, then attn-out
    unsigned short* QKVh = XAhi + (size_t)4096 * 1024;         // [4096][3072]
    float* tsum   = (float*)(QKVh + (size_t)4096 * 3072);      // [32][32][64]
    float* vsuf   = tsum + (size_t)32 * 32 * 64;               // [32][33][64]
    float* partML = vsuf + (size_t)32 * 33 * 64;               // [1856][128]
    float* partO  = partML + (size_t)1856 * 128;               // [1856][4096] (30.4MB)

    float* p1 = (float*)QKVh;                  // split-K half-1 (dead after attn)

    conv_wt_kernel<<<dim3(16, 64), 256, 0, stream>>>(W_qkv, W_out, Wqh, Woh);
    conv_rows_kernel<<<dim3(2048), 256, 0, stream>>>(x, XAhi);

    // fused-batch QKV projection (pure fp16): grid 768 = 3 blocks/CU
    gemm16_kernel<1><<<dim3(24, 32), 256, 0, stream>>>(
        XAhi, Wqh, b_qkv, nullptr, nullptr, QKVh, 4096, 3072, 1024);

    // batched V-suffix sums (hi-only)
    vsuf_part_kernel<<<dim3(32, 8), 256, 0, stream>>>(QKVh, tsum);
    vsuf_scan_kernel<<<dim3(32), 64, 0, stream>>>(tsum, vsuf);

    // batch-fused attention (SEGLEN=10, partials in ws) + combine
    attn_kernel<<<dim3(68, 32), 256, 0, stream>>>(
        QKVh, vsuf, XAhi, partO, partML);
    attn_combine_kernel<<<dim3(22, 32), 256, 0, stream>>>(
        partO, partML, vsuf, XAhi);

    // split-K output projection + combine
    gemm16_kernel<2><<<dim3(8, 64), 256, 0, stream>>>(
        XAhi, Woh, b_out, out, p1, nullptr, 4096, 1024, 512);
    addp_kernel<<<dim3(4096), 256, 0, stream>>>(out, p1);
}

// Round 23
// 127.100 us; speedup vs baseline: 1.0482x; 1.0044x over previous
//
#include <hip/hip_runtime.h>
#include <math.h>

// Problem constants (reference: B=2, S=2048, D=1024, H=16, HD=64)
#define B_ 2
#define S_ 2048
#define D_ 1024
#define H_ 16
#define HD_ 64

typedef unsigned short ushort8 __attribute__((ext_vector_type(8)));
typedef unsigned int u32x4 __attribute__((ext_vector_type(4)));
typedef _Float16 f16x8 __attribute__((ext_vector_type(8)));
typedef _Float16 f16x2 __attribute__((ext_vector_type(2)));
typedef float f32x4 __attribute__((ext_vector_type(4)));

__device__ __forceinline__ unsigned short f2h(float f) {
    union { _Float16 h; unsigned short u; } v;
    v.h = (_Float16)f;                     // native v_cvt_f16_f32, RNE
    return v.u;
}
__device__ __forceinline__ float h2f(unsigned short u) {
    union { unsigned short u; _Float16 h; } v; v.u = u;
    return (float)v.h;
}
__device__ __forceinline__ ushort8 pack2x4h(f32x4 a, f32x4 b) {
    ushort8 hi;
    #pragma unroll
    for (int i = 0; i < 4; ++i) { hi[i] = f2h(a[i]); hi[4 + i] = f2h(b[i]); }
    return hi;
}

// XOR swizzle for [R][64] f16 tiles (128B rows): in-row 16B-chunk permute by row&7.
#define SWZ(row, col) ((((row)) << 6) + (((col)) ^ ((((row)) & 7) << 3)))

__device__ __forceinline__ f32x4 mfma16(f16x8 a, f16x8 b, f32x4 c) {
    return __builtin_amdgcn_mfma_f32_16x16x32_f16(a, b, c, 0, 0, 0);
}

typedef __attribute__((address_space(1))) const void gvoid_t;
typedef __attribute__((address_space(3))) void lvoid_t;
typedef __attribute__((address_space(3))) unsigned short lds_us_t;
__device__ __forceinline__ void gload_lds16(const void* g, void* l) {
    __builtin_amdgcn_global_load_lds((gvoid_t*)g, (lvoid_t*)l, 16, 0, 0);
}
// inline-asm LDS read: opaque to the compiler's waitcnt pass (counted vmcnt survives)
__device__ __forceinline__ f16x8 dsr128(unsigned addr) {
    u32x4 r;
    asm volatile("ds_read_b128 %0, %1" : "=v"(r) : "v"(addr));
    union { u32x4 u; f16x8 h; } cv; cv.u = r; return cv.h;
}

// exp(s*0.125) == 2^(s * 0.125*log2e); raw v_exp_f32 (natively 2^x, no libm tail).
#define EXPSC 0.18033688011f
#define EXP2R(x) __builtin_amdgcn_exp2f(x)

// ---------------------------------------------------------------------------
// conv_rows: fp32 [4096][1024] -> fp16 hi, pre-swizzled (key = row&7)
// ---------------------------------------------------------------------------
__global__ __launch_bounds__(256) void conv_rows_kernel(
    const float* __restrict__ in, unsigned short* __restrict__ ohi)
{
    const int id = blockIdx.x * 256 + threadIdx.x;   // [0, 4096*128)
    const int r = id >> 7, c = id & 127;
    const float* s = in + (size_t)r * 1024 + c * 8;
    f32x4 v0 = *(const f32x4*)s, v1 = *(const f32x4*)(s + 4);
    ushort8 hi = pack2x4h(v0, v1);
    const int oc = (c & ~7) | ((c ^ r) & 7);
    *(ushort8*)&ohi[(size_t)r * 1024 + oc * 8] = hi;
}

// ---------------------------------------------------------------------------
// conv_wt (merged, hi-only): grid (16, 64): y<48 -> W_qkv (ldw 3072), else
// W_out (ldw 1024). fp32 -> Wt fp16 hi [N][1024], transposed + pre-swizzled.
// ---------------------------------------------------------------------------
__global__ __launch_bounds__(256) void conv_wt_kernel(
    const float* __restrict__ Wq, const float* __restrict__ Wo,
    unsigned short* __restrict__ Wqh, unsigned short* __restrict__ Woh)
{
    __shared__ float T[64][65];
    const float* W; int ldw, ny;
    unsigned short *oh;
    if (blockIdx.y < 48) { W = Wq; ldw = 3072; ny = blockIdx.y * 64; oh = Wqh; }
    else                 { W = Wo; ldw = 1024; ny = (blockIdx.y - 48) * 64; oh = Woh; }
    const int tid = threadIdx.x;
    const int kx = blockIdx.x * 64;
    const int kl = tid >> 2, c0 = (tid & 3) * 16;
    const float* s = W + (size_t)(kx + kl) * ldw + ny + c0;
    #pragma unroll
    for (int i = 0; i < 4; ++i) *(f32x4*)&T[kl][c0 + 4 * i] = *(const f32x4*)(s + 4 * i);
    __syncthreads();
    const int nl = tid >> 2, jj = (tid & 3) * 2;
    #pragma unroll
    for (int p = 0; p < 2; ++p) {
        const int j = jj + p;
        f32x4 a, b;
        #pragma unroll
        for (int i = 0; i < 4; ++i) a[i] = T[j * 8 + i][nl];
        #pragma unroll
        for (int i = 0; i < 4; ++i) b[i] = T[j * 8 + 4 + i][nl];
        ushort8 hi = pack2x4h(a, b);
        const int row = ny + nl;
        const int chunk = blockIdx.x * 8 + (j ^ (nl & 7));
        *(ushort8*)&oh[(size_t)row * 1024 + chunk * 8] = hi;
    }
}

// ---------------------------------------------------------------------------
// Pure fp16 MFMA GEMM (1-term, r16-r22 proven): C = Ah @ Bth^T (+ bias).
// 128x128 tile, BK=32, 2 x 16KB LDS dbuf, 4 blocks/CU, counted vmcnt(4).
// OUTMODE 1: fp16 hi out (+bias). OUTMODE 2: split-K fp32.
// ---------------------------------------------------------------------------
template<int OUTMODE>
__global__ __launch_bounds__(256, 4) void gemm16_kernel(
    const unsigned short* __restrict__ Ah, const unsigned short* __restrict__ Bth,
    const float* __restrict__ bias, float* __restrict__ Cf, float* __restrict__ Cf1,
    unsigned short* __restrict__ Ohi,
    int M, int N, int K)
{
    __shared__ __align__(16) unsigned short lds[16384];   // 32KB: 2 x 16KB buffers

    const int tid = threadIdx.x, lane = tid & 63, w = tid >> 6;
    const int wm = w >> 1, wn = w & 1;
    const int gx = gridDim.x, nwg = gx * gridDim.y;
    const int lin = blockIdx.y * gx + blockIdx.x;
    const int nl = (lin & 7) * (nwg >> 3) + (lin >> 3);
    int mblk = nl / gx;
    int koff = 0;
    float* Cfw = Cf;
    bool dobias = (OUTMODE != 2);
    if (OUTMODE == 2) {
        const int halfrows = (int)(gridDim.y >> 1);
        if (mblk >= halfrows) { mblk -= halfrows; koff = 512; Cfw = Cf1; dobias = false; }
        else dobias = true;
    }
    const int m0 = mblk * 128, n0 = (nl % gx) * 128;
    const int col = lane & 15, g = lane >> 4;
    const int NT = K >> 5;

    const int sr0 = (w * 2 + 0) * 16 + (lane >> 2);
    const int sr1 = (w * 2 + 1) * 16 + (lane >> 2);
    const int scp = lane & 3;

    auto stage = [&](int tt) {
        unsigned short* dst = &lds[(tt & 1) * 8192];
        const int hi8 = (tt >> 1) * 8;
        const int tb4 = (tt & 1) << 2;
        #pragma unroll
        for (int q = 0; q < 2; ++q) {
            const int r = q ? sr1 : sr0;
            const int p = hi8 + ((tb4 ^ (r & 4)) | (scp ^ ((r >> 2) & 3)));
            const size_t go = (size_t)p * 8 + koff;
            const int slotb = (w * 2 + q) * 512;
            gload_lds16(Ah  + (size_t)(m0 + r) * 1024 + go, dst + 0    + slotb);
            gload_lds16(Bth + (size_t)(n0 + r) * 1024 + go, dst + 4096 + slotb);
        }
    };

    const unsigned ldsb = (unsigned)(size_t)(lds_us_t*)lds;
    const unsigned sk = (unsigned)(((g ^ (col & 3) ^ ((col >> 2) & 3)) & 3) << 4);
    const unsigned aB = ldsb + (unsigned)((wm * 64 + col) * 64) + sk;
    const unsigned bB = ldsb + 8192u + (unsigned)((wn * 64 + col) * 64) + sk;

    f32x4 acc[4][4] = {};

    stage(0);
    stage(1);

    for (int tt = 0; tt < NT; ++tt) {
        if (tt + 1 < NT) asm volatile("s_waitcnt vmcnt(4)" ::: "memory");
        else             asm volatile("s_waitcnt vmcnt(0)" ::: "memory");
        __builtin_amdgcn_s_barrier();
        __builtin_amdgcn_sched_barrier(0);
        const unsigned bo = (unsigned)((tt & 1) * 16384);

        f16x8 a[4], b[4];
        #pragma unroll
        for (int i = 0; i < 4; ++i) a[i] = dsr128(aB + bo + i * 1024u);
        #pragma unroll
        for (int i = 0; i < 4; ++i) b[i] = dsr128(bB + bo + i * 1024u);

        asm volatile("s_waitcnt lgkmcnt(0)" ::: "memory");
        __builtin_amdgcn_sched_barrier(0);
        __builtin_amdgcn_s_setprio(1);
        #pragma unroll
        for (int mi = 0; mi < 4; ++mi)
            #pragma unroll
            for (int nj = 0; nj < 4; ++nj)
                acc[mi][nj] = mfma16(a[mi], b[nj], acc[mi][nj]);
        __builtin_amdgcn_s_setprio(0);
        __builtin_amdgcn_s_barrier();
        __builtin_amdgcn_sched_barrier(0);
        if (tt + 2 < NT) stage(tt + 2);
    }

    // ---- epilogue: per-wave LDS transpose in two 32-row halves ----
    __syncthreads();
    float* ow = (float*)((char*)lds + w * 8192);   // [32][64] fp32 per wave
    const int nc = (lane & 7) * 8;
    const int nabs = n0 + wn * 64 + nc;
    f32x4 bi0 = {}, bi1 = {};
    if (dobias) { bi0 = *(const f32x4*)&bias[nabs]; bi1 = *(const f32x4*)&bias[nabs + 4]; }
    #pragma unroll
    for (int half = 0; half < 2; ++half) {
        __builtin_amdgcn_wave_barrier();
        #pragma unroll
        for (int ml = 0; ml < 2; ++ml)
            #pragma unroll
            for (int nj = 0; nj < 4; ++nj)
                #pragma unroll
                for (int r = 0; r < 4; ++r)
                    ow[(ml * 16 + g * 4 + r) * 64 + nj * 16 + col] = acc[half * 2 + ml][nj][r];
        __builtin_amdgcn_wave_barrier();
        #pragma unroll
        for (int it = 0; it < 4; ++it) {
            const int rl = it * 8 + (lane >> 3);
            f32x4 v0 = *(const f32x4*)&ow[rl * 64 + nc];
            f32x4 v1 = *(const f32x4*)&ow[rl * 64 + nc + 4];
            if (dobias) { v0 += bi0; v1 += bi1; }
            const int m = m0 + wm * 64 + half * 32 + rl;
            if (OUTMODE == 1) {
                ushort8 hi = pack2x4h(v0, v1);
                const int chunk = (lane & 7) ^ (m & 7);
                *(ushort8*)&Ohi[(size_t)m * N + n0 + wn * 64 + chunk * 8] = hi;
            } else {
                *(f32x4*)&Cfw[(size_t)m * N + nabs] = v0;
                *(f32x4*)&Cfw[(size_t)m * N + nabs + 4] = v1;
            }
        }
        __builtin_amdgcn_wave_barrier();
    }
}

// ---------------------------------------------------------------------------
// out += p1   (split-K combine)
// ---------------------------------------------------------------------------
__global__ __launch_bounds__(256) void addp_kernel(
    float* __restrict__ out, const float* __restrict__ p1)
{
    const size_t idx = ((size_t)blockIdx.x * 256 + threadIdx.x) * 4;
    f32x4 v = *(const f32x4*)&out[idx];
    f32x4 u = *(const f32x4*)&p1[idx];
    v += u;
    *(f32x4*)&out[idx] = v;
}

// ---------------------------------------------------------------------------
// V suffix tile sums (hi-only), batched: grid (32, 8); blockIdx.x = b*16+h
// ---------------------------------------------------------------------------
__global__ __launch_bounds__(256) void vsuf_part_kernel(
    const unsigned short* __restrict__ qh, float* __restrict__ tsum)
{
    const int bh = blockIdx.x, tg = blockIdx.y;
    const int b = bh >> 4, h = bh & 15;
    const unsigned short* qhB = qh + (size_t)b * 2048 * 3072;
    const int tl = threadIdx.x >> 6, lane = threadIdx.x & 63;
    const int t = tg * 4 + tl;
    const int dgrp = lane & 7, rr = lane >> 3;
    const int colbase = h * 192 + 128;
    float sacc[8] = {};
    for (int kk = 0; kk < 8; ++kk) {
        const int row = t * 64 + rr + kk * 8;
        const size_t off = (size_t)row * 3072 + colbase + ((dgrp ^ rr) << 3);
        ushort8 vh = *(const ushort8*)&qhB[off];
        #pragma unroll
        for (int e = 0; e < 8; ++e) sacc[e] += h2f(vh[e]);
    }
    #pragma unroll
    for (int off = 8; off < 64; off <<= 1)
        #pragma unroll
        for (int e = 0; e < 8; ++e) sacc[e] += __shfl_xor(sacc[e], off);
    if (rr == 0) {
        float* dst = &tsum[((size_t)bh * 32 + t) * 64 + dgrp * 8];
        f32x4 v0, v1;
        #pragma unroll
        for (int e = 0; e < 4; ++e) { v0[e] = sacc[e]; v1[e] = sacc[4 + e]; }
        *(f32x4*)dst = v0;
        *(f32x4*)(dst + 4) = v1;
    }
}

__global__ __launch_bounds__(64) void vsuf_scan_kernel(
    const float* __restrict__ tsum, float* __restrict__ vsuf)
{
    const int bh = blockIdx.x, d = threadIdx.x;   // 32 blocks x 64 thr
    float acc = 0.f;
    vsuf[((size_t)bh * 33 + 32) * 64 + d] = 0.f;
    for (int t = 31; t >= 0; --t) {
        acc += tsum[((size_t)bh * 32 + t) * 64 + d];
        vsuf[((size_t)bh * 33 + t) * 64 + d] = acc;
    }
}

// ---------------------------------------------------------------------------
// Causal-skip MFMA flash attention, BATCH-FUSED, QBLK=64, SEGLEN=8 (r23:
// max job 10->8 tiles; occupancy-decay-tail model, confirmed r22).
// Per bh: jobs 0..71 = segments of q-tiles i>=8 (ns=(i+8)/8, <=8 tiles);
// jobs 72..79 = direct i = 79-job (7..0). grid (80, 32) = 2560 blocks.
// K/V LDS double-buffered, 1 barrier/tile. Fixed-m=0 softmax, raw v_exp.
// ---------------------------------------------------------------------------
__global__ __launch_bounds__(256, 4) void attn_kernel(
    const unsigned short* __restrict__ qh,
    const float* __restrict__ vsuf,
    unsigned short* __restrict__ ohi,
    float* __restrict__ partO, float* __restrict__ partML)
{
    __shared__ __align__(16) unsigned short lds[20480];   // 40 KB

    const int tid = threadIdx.x, lane = tid & 63, w = tid >> 6;
    const int g = lane >> 4, oct = g * 8, col = lane & 15;
    const int bh = blockIdx.y;
    const int b = bh >> 4, h = bh & 15;
    const unsigned short* qhB = qh + (size_t)b * 2048 * 3072;
    const float* vsufB = vsuf + (size_t)bh * 33 * 64;
    const int brow = b * 2048;
    const int kp = tid & 31, dg = tid >> 5;

    const int job = blockIdx.x;
    int i = 0, s = 0, slot = -1;
    if (job < 72) {
        int r = job, cum = 0;
        for (int ii = 8; ii < 32; ++ii) {
            const int ns = (ii + 8) / 8;           // ceil((ii+1)/8)
            if (r < cum + ns) { i = ii; s = r - cum; break; }
            cum += ns;
        }
        slot = bh * 72 + job;
    } else {
        i = 79 - job;                  // 7..0
    }
    const int q0 = i * 64;
    const int ntile_all = i + 1;
    const int t_begin = s * 8;
    const int t_end = (slot < 0) ? ntile_all : min(t_begin + 8, ntile_all);
    const bool isseg = (slot >= 0);

    auto gloadK = [&](int ktbase, unsigned kb) {
        #pragma unroll
        for (int j = 0; j < 2; ++j) {
            const int cc = w * 2 + j;
            const int row = ktbase + cc * 8 + (lane >> 3);
            gload_lds16(qhB + (size_t)row * 3072 + h * 192 + 64 + (lane & 7) * 8,
                        &lds[kb + cc * 512]);
        }
    };
    auto vload = [&](int ktbase, f16x8& vA, f16x8& vB) {
        const int r0 = ktbase + 2 * kp, r1 = r0 + 1;
        const int pA = dg ^ (r0 & 7), pB = dg ^ (r1 & 7);
        vA = *(const f16x8*)&qhB[(size_t)r0 * 3072 + h * 192 + 128 + pA * 8];
        vB = *(const f16x8*)&qhB[(size_t)r1 * 3072 + h * 192 + 128 + pB * 8];
    };
    auto vwrite = [&](f16x8 vA, f16x8 vB, unsigned vb) {
        #pragma unroll
        for (int e = 0; e < 8; ++e) {
            const int d = dg * 8 + e;
            f16x2 pr; pr[0] = vA[e]; pr[1] = vB[e];
            *(f16x2*)&lds[vb + SWZ(d, 2 * kp)] = pr;
        }
    };

    // ---- stage Q tile (hi only) into K0 region [0,4096) shorts ----
    #pragma unroll
    for (int j = 0; j < 2; ++j) {
        const int cc = w * 2 + j;
        const int row = q0 + cc * 8 + (lane >> 3);
        gload_lds16(qhB + (size_t)row * 3072 + h * 192 + (lane & 7) * 8,
                    &lds[cc * 512]);
    }
    f16x8 vA, vB;
    vload(t_begin * 64, vA, vB);
    __syncthreads();                          // Q published
    f16x8 qfh[2];
    {
        const int qrow = w * 16 + col;
        qfh[0] = *(const f16x8*)&lds[SWZ(qrow, oct)];
        qfh[1] = *(const f16x8*)&lds[SWZ(qrow, 32 + oct)];
    }
    __syncthreads();                          // all Q reads done before K0 overwrite
    gloadK(t_begin * 64, 0u);                 // K(t_begin) -> K0
    vwrite(vA, vB, 8192u);                    // V(t_begin) -> Vt0
    __syncthreads();                          // K0 (vmcnt drain) + Vt0 published

    const int qg = q0 + w * 16 + col;
    float l_run = 0.f;                 // per-lane partial (this lane's 16 keys/tile)
    f32x4 oacc[4] = {};

    int cur = 0;
    for (int t = t_begin; t < t_end; ++t) {
        const int kt = t * 64;
        const bool pf = (t + 1 < t_end);
        const unsigned kb  = (unsigned)(cur * 4096);          // K[cur]
        const unsigned vb  = 8192u + (unsigned)(cur * 4096);  // Vt[cur]
        const unsigned kbn = (unsigned)((cur ^ 1) * 4096);
        const unsigned vbn = 8192u + (unsigned)((cur ^ 1) * 4096);

        f16x8 vA2, vB2;
        if (pf) { vload(kt + 64, vA2, vB2); gloadK(kt + 64, kbn); }

        // ---- scores: S^T[key][q] = K·Q (1-term fp16) ----
        f32x4 sacc[4] = {};
        #pragma unroll
        for (int c = 0; c < 2; ++c)
            #pragma unroll
            for (int t4 = 0; t4 < 4; ++t4) {
                const int krow = t4 * 16 + col;
                f16x8 khf = *(const f16x8*)&lds[kb + SWZ(krow, c * 32 + oct)];
                sacc[t4] = mfma16(khf, qfh[c], sacc[t4]);
            }

        // ---- softmax, fixed m=0: raw v_exp_f32 + pack + accumulate ----
        unsigned short* Pw = &lds[16384 + w * 1024];
        if (t == ntile_all - 1) {   // diagonal tile: masked logit -> weight 1
            #pragma unroll
            for (int t4 = 0; t4 < 4; ++t4)
                #pragma unroll
                for (int rp = 0; rp < 2; ++rp) {
                    const int k0 = kt + t4 * 16 + g * 4 + rp * 2;
                    float s0 = sacc[t4][rp * 2]     * EXPSC;
                    float s1 = sacc[t4][rp * 2 + 1] * EXPSC;
                    if (k0 > qg)     s0 = 0.0f;
                    if (k0 + 1 > qg) s1 = 0.0f;
                    float e0 = EXP2R(s0), e1 = EXP2R(s1);
                    l_run += e0 + e1;
                    f16x2 pk; pk[0] = (_Float16)e0; pk[1] = (_Float16)e1;
                    *(f16x2*)&Pw[SWZ(col, t4 * 16 + g * 4 + rp * 2)] = pk;
                }
        } else {
            #pragma unroll
            for (int t4 = 0; t4 < 4; ++t4)
                #pragma unroll
                for (int rp = 0; rp < 2; ++rp) {
                    float e0 = EXP2R(sacc[t4][rp * 2]     * EXPSC);
                    float e1 = EXP2R(sacc[t4][rp * 2 + 1] * EXPSC);
                    l_run += e0 + e1;
                    f16x2 pk; pk[0] = (_Float16)e0; pk[1] = (_Float16)e1;
                    *(f16x2*)&Pw[SWZ(col, t4 * 16 + g * 4 + rp * 2)] = pk;
                }
        }

        // V(t+1) -> other buffer (no barrier needed; PV below reads cur buffer)
        if (pf) vwrite(vA2, vB2, vbn);

        __builtin_amdgcn_wave_barrier();      // pin own Pw writes before reads

        // ---- PV: O^T[d][q] += Vt · P (no rescale; m fixed) ----
        #pragma unroll
        for (int c = 0; c < 2; ++c) {
            f16x8 pfv = *(const f16x8*)&Pw[SWZ(col, c * 32 + oct)];
            #pragma unroll
            for (int dt = 0; dt < 4; ++dt) {
                f16x8 vh = *(const f16x8*)&lds[vb + SWZ(dt * 16 + col, c * 32 + oct)];
                oacc[dt] = mfma16(vh, pfv, oacc[dt]);
            }
        }

        __syncthreads();                      // publish K(t+1) + Vt(t+1); all reads done
        cur ^= 1;
    }

    // ---- reduce l across the 4 key-groups (once, not per tile) ----
    float lt = l_run;
    lt += __shfl_xor(lt, 16);
    lt += __shfl_xor(lt, 32);

    if (isseg) {
        float* po = partO + (size_t)slot * 4096;
        #pragma unroll
        for (int dt = 0; dt < 4; ++dt)
            #pragma unroll
            for (int r = 0; r < 4; ++r)
                po[(dt * 16 + g * 4 + r) * 64 + w * 16 + col] = oacc[dt][r];
        if (g == 0) partML[(size_t)slot * 128 + w * 16 + col] = lt;
        return;
    }

    // ---- direct: masked tail weight = 1 per key, exact ----
    lt += (float)(S_ - q0 - 64);
    {
        const float* vs = vsufB + (size_t)(i + 1) * 64;
        #pragma unroll
        for (int dt = 0; dt < 4; ++dt)
            #pragma unroll
            for (int r = 0; r < 4; ++r)
                oacc[dt][r] += vs[dt * 16 + g * 4 + r];
    }
    const float inv = 1.f / lt;
    float* ow = (float*)&lds[w * 4096];
    const int q = lane >> 2, jj = lane & 3;
    #pragma unroll
    for (int half = 0; half < 2; ++half) {
        __builtin_amdgcn_wave_barrier();
        #pragma unroll
        for (int t4 = 0; t4 < 2; ++t4)
            #pragma unroll
            for (int r = 0; r < 4; ++r)
                ow[col * 40 + t4 * 16 + g * 4 + r] = oacc[half * 2 + t4][r] * inv;
        __builtin_amdgcn_wave_barrier();
        f32x4 v0 = *(const f32x4*)&ow[q * 40 + jj * 8];
        f32x4 v1 = *(const f32x4*)&ow[q * 40 + jj * 8 + 4];
        ushort8 hi = pack2x4h(v0, v1);
        const int m = brow + q0 + w * 16 + q;
        const int chunk = (half * 4 + jj) ^ (m & 7);
        *(ushort8*)&ohi[(size_t)m * 1024 + h * 64 + chunk * 8] = hi;
    }
}

// ---------------------------------------------------------------------------
// Combine partials for split q-tiles (i>=8), batched: grid (24, 32).
// Fixed m=0: lstar = sum l + tailcount, od = sum O + vsuf. nseg = 2..4.
// ---------------------------------------------------------------------------
__global__ __launch_bounds__(256) void attn_combine_kernel(
    const float* __restrict__ partO, const float* __restrict__ partML,
    const float* __restrict__ vsuf,
    unsigned short* __restrict__ ohi)
{
    const int i = 8 + blockIdx.x;               // 8..31
    const int bh = blockIdx.y;
    const int b = bh >> 4, h = bh & 15;
    const float* vsufB = vsuf + (size_t)bh * 33 * 64;
    const int brow = b * 2048;
    const int nseg = (i + 8) / 8;
    int cum = 0;
    for (int j = 8; j < i; ++j) cum += (j + 8) / 8;
    const int slot0 = bh * 72 + cum;
    const int q = threadIdx.x & 63, dgrp = threadIdx.x >> 6;
    const int q0 = i * 64;

    float lstar = (float)(S_ - q0 - 64);        // masked tail, weight 1 each

    float od[16];
    const float* vs = vsufB + (size_t)(i + 1) * 64 + dgrp * 16;
    #pragma unroll
    for (int k = 0; k < 16; ++k) od[k] = vs[k];

    for (int sg = 0; sg < nseg; ++sg) {
        lstar += partML[(size_t)(slot0 + sg) * 128 + q];
        const float* po = partO + (size_t)(slot0 + sg) * 4096 + (size_t)(dgrp * 16) * 64 + q;
        #pragma unroll
        for (int k = 0; k < 16; ++k) od[k] += po[k * 64];
    }

    const float inv = 1.f / lstar;
    f32x4 a0, a1, b0, b1;
    #pragma unroll
    for (int k = 0; k < 4; ++k) {
        a0[k] = od[k] * inv; a1[k] = od[4 + k] * inv;
        b0[k] = od[8 + k] * inv; b1[k] = od[12 + k] * inv;
    }
    ushort8 hi0 = pack2x4h(a0, a1);
    ushort8 hi1 = pack2x4h(b0, b1);
    const int mrow = brow + q0 + q;
    const int c0 = (dgrp * 2) ^ (mrow & 7);
    const int c1 = (dgrp * 2 + 1) ^ (mrow & 7);
    const size_t base = (size_t)mrow * 1024 + h * 64;
    *(ushort8*)&ohi[base + c0 * 8] = hi0;
    *(ushort8*)&ohi[base + c1 * 8] = hi1;
}

// ---------------------------------------------------------------------------
extern "C" void kernel_launch(void* const* d_in, const int* in_sizes, int n_in,
                              void* d_out, int out_size, void* d_ws, size_t ws_size,
                              hipStream_t stream) {
    const float* x     = (const float*)d_in[0];   // [B,S,D]
    const float* W_qkv = (const float*)d_in[1];   // [D,3D]
    const float* b_qkv = (const float*)d_in[2];   // [3D]
    const float* W_out = (const float*)d_in[3];   // [D,D]
    const float* b_out = (const float*)d_in[4];   // [D]
    float* out = (float*)d_out;                   // [B,S,D]

    // ws layout (~81.4 MB; >= 84.2 MB proven since r8's fused path ran)
    unsigned short* us  = (unsigned short*)d_ws;
    unsigned short* Wqh = us;                                  // [3072][1024]
    unsigned short* Woh = Wqh + (size_t)3072 * 1024;           // [1024][1024]
    unsigned short* XAhi = Woh + (size_t)1024 * 1024;          // [4096][1024] X, then attn-out
    unsigned short* QKVh = XAhi + (size_t)4096 * 1024;         // [4096][3072]
    float* tsum   = (float*)(QKVh + (size_t)4096 * 3072);      // [32][32][64]
    float* vsuf   = tsum + (size_t)32 * 32 * 64;               // [32][33][64]
    float* partML = vsuf + (size_t)32 * 33 * 64;               // [2304][128]
    float* partO  = partML + (size_t)2304 * 128;               // [2304][4096] (37.7MB)

    float* p1 = (float*)QKVh;                  // split-K half-1 (dead after attn)

    conv_wt_kernel<<<dim3(16, 64), 256, 0, stream>>>(W_qkv, W_out, Wqh, Woh);
    conv_rows_kernel<<<dim3(2048), 256, 0, stream>>>(x, XAhi);

    // fused-batch QKV projection (pure fp16): grid 768 = 3 blocks/CU
    gemm16_kernel<1><<<dim3(24, 32), 256, 0, stream>>>(
        XAhi, Wqh, b_qkv, nullptr, nullptr, QKVh, 4096, 3072, 1024);

    // batched V-suffix sums (hi-only)
    vsuf_part_kernel<<<dim3(32, 8), 256, 0, stream>>>(QKVh, tsum);
    vsuf_scan_kernel<<<dim3(32), 64, 0, stream>>>(tsum, vsuf);

    // batch-fused attention (SEGLEN=8, partials in ws) + combine
    attn_kernel<<<dim3(80, 32), 256, 0, stream>>>(
        QKVh, vsuf, XAhi, partO, partML);
    attn_combine_kernel<<<dim3(24, 32), 256, 0, stream>>>(
        partO, partML, vsuf, XAhi);

    // split-K output projection + combine
    gemm16_kernel<2><<<dim3(8, 64), 256, 0, stream>>>(
        XAhi, Woh, b_out, out, p1, nullptr, 4096, 1024, 512);
    addp_kernel<<<dim3(4096), 256, 0, stream>>>(out, p1);
}